// Round 1
// baseline (84323.541 us; speedup 1.0000x reference)
//
#include <hip/hip_runtime.h>
#include <math.h>

#define TPB 256
#define NBLK 512

typedef unsigned short u16;
typedef float f32x4 __attribute__((ext_vector_type(4)));
typedef short s16x8 __attribute__((ext_vector_type(8)));

// ---------------- helpers ----------------
__device__ __forceinline__ u16 f2bf(float f) {
  unsigned u = __float_as_uint(f);
  unsigned r = (u + 0x7FFFu + ((u >> 16) & 1u)) >> 16;   // RNE
  return (u16)r;
}
__device__ __forceinline__ float bf2f(u16 b) { return __uint_as_float(((unsigned)b) << 16); }
__device__ __forceinline__ float sigm(float x) { return 1.f / (1.f + expf(-x)); }

__device__ __forceinline__ f32x4 mfma_bf16(s16x8 a, s16x8 b, f32x4 c) {
  return __builtin_amdgcn_mfma_f32_16x16x32_bf16(a, b, c, 0, 0, 0);
}

// ---------------- params ----------------
struct KParams {
  const float* x;        // [1024][336][16]
  float* out;            // [1024][168]
  unsigned long long* cx;  // per-group barrier counters (stride 32 ULL = 256B)
  unsigned long long* cg;  // global barrier counter
  float* y;              // [1024] decoder feedback
  float* c0; float* c1;  // [1024][512] cell states (plain layout)
  u16* h0h[2]; u16* h0l[2];  // h frag-layout [16][1024][32] bf16 hi/lo, ping-pong
  u16* h1h[2]; u16* h1l[2];
  const u16 *we0h, *we0l;   // [17][2048][32]
  const u16 *we1h, *we1l;   // [32][2048][32]
  const u16 *wd0h, *wd0l;   // [16][2048][32]
  const u16 *wd1h, *wd1l;   // [32][2048][32]
  const u16 *wfh,  *wfl;    // [16][256][32]
  const float *be0, *be1, *bd0, *bd1, *wyp;  // permuted biases [2048], dec0 y-column [2048]
  const float *fcb1, *fcw2, *fcb2;           // raw fp32 from inputs
};

// ---------------- init kernels ----------------
__global__ void zero_ws(uint4* p, long n) {
  uint4 z = {0u, 0u, 0u, 0u};
  for (long i = (long)blockIdx.x * blockDim.x + threadIdx.x; i < n; i += (long)gridDim.x * blockDim.x)
    p[i] = z;
}

// Build fragment-major, gate-interleaved, hi/lo-split weights.
// dst[c][n'][kk], n' = h*4+g  (orig row n = g*512+h), k = c*32+kk.
// mode 0 (enc0): c<16 -> Whh (K=512 from h); c==16 -> Wih (K=16, padded to 32)
// mode 1 (enc1/dec1): c<16 -> Wih (K=512 from lower-layer h); c>=16 -> Whh
// mode 2 (dec0): Whh only; also wy_p[n'] = Wih[n][0]
__global__ void prep_w(const float* __restrict__ Wih, const float* __restrict__ Whh,
                       const float* __restrict__ bias,
                       u16* __restrict__ dhi, u16* __restrict__ dlo,
                       float* __restrict__ bias_p, float* __restrict__ wy_p,
                       int mode, int nchunks) {
  long total = (long)nchunks * 2048 * 32;
  for (long i = (long)blockIdx.x * blockDim.x + threadIdx.x; i < total; i += (long)gridDim.x * blockDim.x) {
    int kk = (int)(i & 31);
    long r1 = i >> 5;
    int n = (int)(r1 & 2047);
    int c = (int)(r1 >> 11);
    int h = n >> 2, g = n & 3;
    int no = g * 512 + h;
    float wv;
    if (mode == 0)      wv = (c < 16) ? Whh[no * 512 + c * 32 + kk] : (kk < 16 ? Wih[no * 16 + kk] : 0.f);
    else if (mode == 1) wv = (c < 16) ? Wih[no * 512 + c * 32 + kk] : Whh[no * 512 + (c - 16) * 32 + kk];
    else                wv = Whh[no * 512 + c * 32 + kk];
    u16 hb = f2bf(wv);
    dhi[i] = hb;
    dlo[i] = f2bf(wv - bf2f(hb));
    if (i < 2048) {
      int nn = (int)i, hh = nn >> 2, gg = nn & 3, noo = gg * 512 + hh;
      bias_p[nn] = bias[noo];
      if (mode == 2) wy_p[nn] = Wih[noo];  // dec_Wih0 is [2048][1]
    }
  }
}

__global__ void prep_fc(const float* __restrict__ W1, u16* __restrict__ dhi, u16* __restrict__ dlo) {
  int total = 16 * 256 * 32;
  for (int i = blockIdx.x * blockDim.x + threadIdx.x; i < total; i += gridDim.x * blockDim.x) {
    int kk = i & 31, n = (i >> 5) & 255, c = i >> 13;
    float wv = W1[n * 512 + c * 32 + kk];
    u16 hb = f2bf(wv);
    dhi[i] = hb;
    dlo[i] = f2bf(wv - bf2f(hb));
  }
}

// ---------------- grid barrier ----------------
// Hierarchical monotonic barrier: 64 blocks/group arrive on cx[group]; the
// group-last bumps cg; everyone spins on cg. __threadfence() gives the
// agent-scope release (L2 writeback) / acquire (L1+L2 inv) needed across XCDs.
__device__ __forceinline__ void gbar(const KParams& P, int grp, unsigned long long bi) {
  __syncthreads();
  if (threadIdx.x == 0) {
    __threadfence();
    unsigned long long old =
        __hip_atomic_fetch_add(&P.cx[grp * 32], 1ULL, __ATOMIC_RELAXED, __HIP_MEMORY_SCOPE_AGENT);
    if (old == bi * 64ULL - 1ULL)
      __hip_atomic_fetch_add(P.cg, 1ULL, __ATOMIC_RELAXED, __HIP_MEMORY_SCOPE_AGENT);
    unsigned long long t0 = __builtin_amdgcn_s_memrealtime();
    while (__hip_atomic_load(P.cg, __ATOMIC_RELAXED, __HIP_MEMORY_SCOPE_AGENT) < bi * 8ULL) {
      __builtin_amdgcn_s_sleep(8);
      if (__builtin_amdgcn_s_memrealtime() - t0 > 300000000ULL) {  // ~3 s @100MHz
        P.out[0] = 1e9f;  // sentinel: barrier timeout
        break;
      }
    }
  }
  __syncthreads();
  __threadfence();
}

// ---------------- fused gates GEMM + LSTM cell ----------------
// C[64m x 64n] tile, K = nct*32 (+16 of x if HASX, rank-1 y if HASY).
// A (activations) and B (weights) both bf16 hi/lo split: 3 MFMAs per product.
template <bool TWOA, bool HASX, bool HASY>
__device__ __forceinline__ void lstm_phase(
    const KParams& P, int m_tile, int n_tile, int nct,
    const u16* __restrict__ A1h, const u16* __restrict__ A1l,
    const u16* __restrict__ A2h, const u16* __restrict__ A2l,
    const u16* __restrict__ WBh, const u16* __restrict__ WBl,
    const float* __restrict__ bias_p, const float* __restrict__ wyp,
    int t, float* __restrict__ cbuf, u16* __restrict__ Hh, u16* __restrict__ Hl,
    char* smem) {
  const int tid = threadIdx.x;
  const int w = tid >> 6;
  const int lane = tid & 63;
  const int r = lane & 15;
  const int q = lane >> 4;
  const int m0 = m_tile * 64;
  const int n0 = n_tile * 64;
  u16* sA = (u16*)smem;             // [2 chunk][2 hilo][64 row][40] (pad 32->40 kills LDS conflicts)
  u16* sB = (u16*)(smem + 20480);

  f32x4 acc[4];
#pragma unroll
  for (int mi = 0; mi < 4; ++mi) acc[mi] = (f32x4){0.f, 0.f, 0.f, 0.f};

  const int seg = tid & 3;
  const int row = (tid >> 2) & 63;
  const int nst = nct >> 1;

  for (int s = 0; s < nst; ++s) {
    __syncthreads();
#pragma unroll
    for (int kki = 0; kki < 4; ++kki) {
      const int ch = kki >> 1;
      const int hl = kki & 1;
      const int c = s * 2 + ch;
      const u16* asrc;
      if (!TWOA || c < 16)
        asrc = (hl ? A1l : A1h) + ((c * 1024 + m0 + row) * 32 + seg * 8);
      else
        asrc = (hl ? A2l : A2h) + (((c - 16) * 1024 + m0 + row) * 32 + seg * 8);
      *(uint4*)(sA + ((ch * 2 + hl) * 64 + row) * 40 + seg * 8) = *(const uint4*)asrc;
      const u16* bsrc = (hl ? WBl : WBh) + ((c * 2048 + n0 + row) * 32 + seg * 8);
      *(uint4*)(sB + ((ch * 2 + hl) * 64 + row) * 40 + seg * 8) = *(const uint4*)bsrc;
    }
    __syncthreads();
#pragma unroll
    for (int ch = 0; ch < 2; ++ch) {
      const s16x8 ah = *(const s16x8*)(sA + ((ch * 2 + 0) * 64 + w * 16 + r) * 40 + q * 8);
      const s16x8 al = *(const s16x8*)(sA + ((ch * 2 + 1) * 64 + w * 16 + r) * 40 + q * 8);
#pragma unroll
      for (int mi = 0; mi < 4; ++mi) {
        const s16x8 bh = *(const s16x8*)(sB + ((ch * 2 + 0) * 64 + mi * 16 + r) * 40 + q * 8);
        const s16x8 bl = *(const s16x8*)(sB + ((ch * 2 + 1) * 64 + mi * 16 + r) * 40 + q * 8);
        acc[mi] = mfma_bf16(ah, bh, acc[mi]);
        acc[mi] = mfma_bf16(ah, bl, acc[mi]);
        acc[mi] = mfma_bf16(al, bh, acc[mi]);
      }
    }
  }

  if (HASX) {  // extra K=16 chunk from x_t (padded to 32); B chunk index 16, direct from L2
    s16x8 ah, al;
#pragma unroll
    for (int j = 0; j < 8; ++j) { ah[j] = 0; al[j] = 0; }
    if (q < 2) {
      const float* xp = P.x + (((long)(m0 + w * 16 + r) * 336 + t) * 16 + q * 8);
      float4 v0 = *(const float4*)xp;
      float4 v1 = *(const float4*)(xp + 4);
      float vv[8] = {v0.x, v0.y, v0.z, v0.w, v1.x, v1.y, v1.z, v1.w};
#pragma unroll
      for (int j = 0; j < 8; ++j) {
        u16 hb = f2bf(vv[j]);
        ah[j] = (short)hb;
        al[j] = (short)f2bf(vv[j] - bf2f(hb));
      }
    }
#pragma unroll
    for (int mi = 0; mi < 4; ++mi) {
      long bo = ((long)16 * 2048 + n0 + mi * 16 + r) * 32 + q * 8;
      const s16x8 bh = *(const s16x8*)(WBh + bo);
      const s16x8 bl = *(const s16x8*)(WBl + bo);
      acc[mi] = mfma_bf16(ah, bh, acc[mi]);
      acc[mi] = mfma_bf16(ah, bl, acc[mi]);
      acc[mi] = mfma_bf16(al, bh, acc[mi]);
    }
  }

  // ---- epilogue: gates -> (c,h); tile cols are gate-interleaved n'=h*4+g ----
  __syncthreads();
  float* gbuf = (float*)smem;  // [64][68]
#pragma unroll
  for (int mi = 0; mi < 4; ++mi)
#pragma unroll
    for (int reg = 0; reg < 4; ++reg)
      gbuf[(w * 16 + q * 4 + reg) * 68 + mi * 16 + r] = acc[mi][reg];
  __syncthreads();
#pragma unroll
  for (int kk2 = 0; kk2 < 4; ++kk2) {
    int p = tid + kk2 * 256;
    int ml = p >> 4, hl2 = p & 15;
    float* gp = gbuf + ml * 68 + hl2 * 4;
    int mg = m0 + ml;
    int hg = n_tile * 16 + hl2;
    float g0 = gp[0] + bias_p[n0 + hl2 * 4 + 0];
    float g1 = gp[1] + bias_p[n0 + hl2 * 4 + 1];
    float g2 = gp[2] + bias_p[n0 + hl2 * 4 + 2];
    float g3 = gp[3] + bias_p[n0 + hl2 * 4 + 3];
    if (HASY) {
      float yv = P.y[mg];
      g0 += yv * wyp[n0 + hl2 * 4 + 0];
      g1 += yv * wyp[n0 + hl2 * 4 + 1];
      g2 += yv * wyp[n0 + hl2 * 4 + 2];
      g3 += yv * wyp[n0 + hl2 * 4 + 3];
    }
    float ig = sigm(g0), fg = sigm(g1), gg = tanhf(g2), og = sigm(g3);
    long co = (long)mg * 512 + hg;
    float cn = fg * cbuf[co] + ig * gg;
    cbuf[co] = cn;
    float hv = og * tanhf(cn);
    u16 hb = f2bf(hv);
    u16 lb = f2bf(hv - bf2f(hb));
    long ho = ((long)(hg >> 5) * 1024 + mg) * 32 + (hg & 31);  // frag layout for next GEMM
    Hh[ho] = hb;
    Hl[ho] = lb;
  }
}

// ---------------- FC head: pred = relu(relu(h1@W1^T+b1)@W2^T+b2) ----------------
__device__ __forceinline__ void fc_phase(const KParams& P, int b, const u16* __restrict__ Ah,
                                         const u16* __restrict__ Al, int t, char* smem) {
  const int tid = threadIdx.x;
  const int w = tid >> 6;
  const int lane = tid & 63;
  const int r = lane & 15;
  const int q = lane >> 4;
  const int m0 = b * 16;  // 64 blocks x 16 rows
  f32x4 acc[4];
#pragma unroll
  for (int mi = 0; mi < 4; ++mi) acc[mi] = (f32x4){0.f, 0.f, 0.f, 0.f};
  for (int c = 0; c < 16; ++c) {
    long ao = ((long)c * 1024 + m0 + r) * 32 + q * 8;
    const s16x8 ah = *(const s16x8*)(Ah + ao);
    const s16x8 al = *(const s16x8*)(Al + ao);
#pragma unroll
    for (int mi = 0; mi < 4; ++mi) {
      int n = w * 64 + mi * 16 + r;
      long bo = ((long)c * 256 + n) * 32 + q * 8;
      const s16x8 bh = *(const s16x8*)(P.wfh + bo);
      const s16x8 bl = *(const s16x8*)(P.wfl + bo);
      acc[mi] = mfma_bf16(ah, bh, acc[mi]);
      acc[mi] = mfma_bf16(ah, bl, acc[mi]);
      acc[mi] = mfma_bf16(al, bh, acc[mi]);
    }
  }
  float* hid = (float*)smem;  // [16][264]
#pragma unroll
  for (int mi = 0; mi < 4; ++mi)
#pragma unroll
    for (int reg = 0; reg < 4; ++reg) {
      int rowi = q * 4 + reg, col = w * 64 + mi * 16 + r;
      hid[rowi * 264 + col] = fmaxf(acc[mi][reg] + P.fcb1[col], 0.f);
    }
  __syncthreads();
  float* part = (float*)(smem + 16 * 264 * 4);  // [16][17]
  {
    int m = tid >> 4, sg = tid & 15;
    float s = 0.f;
#pragma unroll
    for (int j = 0; j < 16; ++j) s += hid[m * 264 + sg * 16 + j] * P.fcw2[sg * 16 + j];
    part[m * 17 + sg] = s;
  }
  __syncthreads();
  if (tid < 16) {
    float s = P.fcb2[0];
    for (int sg = 0; sg < 16; ++sg) s += part[tid * 17 + sg];
    float pred = fmaxf(s, 0.f);
    P.y[m0 + tid] = pred;
    P.out[(long)(m0 + tid) * 168 + t] = pred;
  }
}

// ---------------- persistent kernel ----------------
__global__ void __launch_bounds__(TPB, 2) lstm_seq(KParams P) {
  __shared__ __align__(16) char smem[40960];
  const int b = blockIdx.x;
  const int grp = b & 7;          // barrier group / XCD hint
  const int idx = b >> 3;
  const int n_tile = grp * 4 + (idx & 3);  // XCD-sliced N: each group owns a 256-col slice
  const int m_tile = idx >> 2;
  unsigned long long bi = 0;
  int par = 0;

  for (int t = 0; t < 336; ++t) {
    lstm_phase<false, true, false>(P, m_tile, n_tile, 16, P.h0h[par], P.h0l[par], nullptr, nullptr,
                                   P.we0h, P.we0l, P.be0, nullptr, t, P.c0,
                                   P.h0h[par ^ 1], P.h0l[par ^ 1], smem);
    ++bi; gbar(P, grp, bi);
    lstm_phase<true, false, false>(P, m_tile, n_tile, 32, P.h0h[par ^ 1], P.h0l[par ^ 1],
                                   P.h1h[par], P.h1l[par], P.we1h, P.we1l, P.be1, nullptr, 0, P.c1,
                                   P.h1h[par ^ 1], P.h1l[par ^ 1], smem);
    ++bi; gbar(P, grp, bi);
    par ^= 1;
  }
  for (int t = 0; t < 168; ++t) {
    lstm_phase<false, false, true>(P, m_tile, n_tile, 16, P.h0h[par], P.h0l[par], nullptr, nullptr,
                                   P.wd0h, P.wd0l, P.bd0, P.wyp, 0, P.c0,
                                   P.h0h[par ^ 1], P.h0l[par ^ 1], smem);
    ++bi; gbar(P, grp, bi);
    lstm_phase<true, false, false>(P, m_tile, n_tile, 32, P.h0h[par ^ 1], P.h0l[par ^ 1],
                                   P.h1h[par], P.h1l[par], P.wd1h, P.wd1l, P.bd1, nullptr, 0, P.c1,
                                   P.h1h[par ^ 1], P.h1l[par ^ 1], smem);
    ++bi; gbar(P, grp, bi);
    if (b < 64) fc_phase(P, b, P.h1h[par ^ 1], P.h1l[par ^ 1], t, smem);
    ++bi; gbar(P, grp, bi);
    par ^= 1;
  }
}

// ---------------- host ----------------
extern "C" void kernel_launch(void* const* d_in, const int* in_sizes, int n_in,
                              void* d_out, int out_size, void* d_ws, size_t ws_size,
                              hipStream_t stream) {
  const float* x     = (const float*)d_in[0];
  const float* eWih0 = (const float*)d_in[1];
  const float* eWhh0 = (const float*)d_in[2];
  const float* eb0   = (const float*)d_in[3];
  const float* eWih1 = (const float*)d_in[4];
  const float* eWhh1 = (const float*)d_in[5];
  const float* eb1   = (const float*)d_in[6];
  const float* dWih0 = (const float*)d_in[7];
  const float* dWhh0 = (const float*)d_in[8];
  const float* db0   = (const float*)d_in[9];
  const float* dWih1 = (const float*)d_in[10];
  const float* dWhh1 = (const float*)d_in[11];
  const float* db1   = (const float*)d_in[12];
  const float* fcW1  = (const float*)d_in[13];
  const float* fcb1  = (const float*)d_in[14];
  const float* fcW2  = (const float*)d_in[15];
  const float* fcb2  = (const float*)d_in[16];

  char* ws = (char*)d_ws;
  unsigned long long* cx = (unsigned long long*)(ws + 0);     // 8 counters, 256B apart
  unsigned long long* cg = (unsigned long long*)(ws + 2048);
  float* y  = (float*)(ws + 4096);
  float* c0 = (float*)(ws + 8192);
  float* c1 = (float*)(ws + 8192 + 2097152L);
  char* hb = ws + 8192 + 2 * 2097152L;
  u16* h0h0 = (u16*)(hb + 0L * 1048576);
  u16* h0h1 = (u16*)(hb + 1L * 1048576);
  u16* h0l0 = (u16*)(hb + 2L * 1048576);
  u16* h0l1 = (u16*)(hb + 3L * 1048576);
  u16* h1h0 = (u16*)(hb + 4L * 1048576);
  u16* h1h1 = (u16*)(hb + 5L * 1048576);
  u16* h1l0 = (u16*)(hb + 6L * 1048576);
  u16* h1l1 = (u16*)(hb + 7L * 1048576);
  char* wb = hb + 8L * 1048576;
  u16* we0h = (u16*)wb; wb += 2228224L;
  u16* we0l = (u16*)wb; wb += 2228224L;
  u16* we1h = (u16*)wb; wb += 4194304L;
  u16* we1l = (u16*)wb; wb += 4194304L;
  u16* wd0h = (u16*)wb; wb += 2097152L;
  u16* wd0l = (u16*)wb; wb += 2097152L;
  u16* wd1h = (u16*)wb; wb += 4194304L;
  u16* wd1l = (u16*)wb; wb += 4194304L;
  u16* wfh  = (u16*)wb; wb += 262144L;
  u16* wfl  = (u16*)wb; wb += 262144L;
  float* be0 = (float*)wb; wb += 8192L;
  float* be1 = (float*)wb; wb += 8192L;
  float* bd0 = (float*)wb; wb += 8192L;
  float* bd1 = (float*)wb; wb += 8192L;
  float* wyp = (float*)wb; wb += 8192L;

  long zbytes = 8192L + 2L * 2097152L + 8L * 1048576L;  // barrier+y+c+h
  zero_ws<<<1024, 256, 0, stream>>>((uint4*)ws, zbytes / 16);
  prep_w<<<2048, 256, 0, stream>>>(eWih0, eWhh0, eb0, we0h, we0l, be0, nullptr, 0, 17);
  prep_w<<<2048, 256, 0, stream>>>(eWih1, eWhh1, eb1, we1h, we1l, be1, nullptr, 1, 32);
  prep_w<<<2048, 256, 0, stream>>>(dWih0, dWhh0, db0, wd0h, wd0l, bd0, wyp, 2, 16);
  prep_w<<<2048, 256, 0, stream>>>(dWih1, dWhh1, db1, wd1h, wd1l, bd1, nullptr, 1, 32);
  prep_fc<<<512, 256, 0, stream>>>(fcW1, wfh, wfl);

  KParams P;
  P.x = x; P.out = (float*)d_out; P.cx = cx; P.cg = cg; P.y = y; P.c0 = c0; P.c1 = c1;
  P.h0h[0] = h0h0; P.h0h[1] = h0h1; P.h0l[0] = h0l0; P.h0l[1] = h0l1;
  P.h1h[0] = h1h0; P.h1h[1] = h1h1; P.h1l[0] = h1l0; P.h1l[1] = h1l1;
  P.we0h = we0h; P.we0l = we0l; P.we1h = we1h; P.we1l = we1l;
  P.wd0h = wd0h; P.wd0l = wd0l; P.wd1h = wd1h; P.wd1l = wd1l;
  P.wfh = wfh; P.wfl = wfl;
  P.be0 = be0; P.be1 = be1; P.bd0 = bd0; P.bd1 = bd1; P.wyp = wyp;
  P.fcb1 = fcb1; P.fcw2 = fcW2; P.fcb2 = fcb2;

  lstm_seq<<<NBLK, TPB, 0, stream>>>(P);
}

// Round 3
// 27127.249 us; speedup vs baseline: 3.1084x; 3.1084x over previous
//
#include <hip/hip_runtime.h>
#include <math.h>

#define TPB 256
#define NBLK 256

typedef unsigned short u16;
typedef float f32x4 __attribute__((ext_vector_type(4)));
typedef short s16x8 __attribute__((ext_vector_type(8)));
typedef unsigned int u32x4 __attribute__((ext_vector_type(4)));

// ---------------- helpers ----------------
__device__ __forceinline__ u16 f2bf(float f) {
  unsigned u = __float_as_uint(f);
  unsigned r = (u + 0x7FFFu + ((u >> 16) & 1u)) >> 16;   // RNE
  return (u16)r;
}
__device__ __forceinline__ float bf2f(u16 b) { return __uint_as_float(((unsigned)b) << 16); }
__device__ __forceinline__ float sigm(float x) { return 1.f / (1.f + expf(-x)); }

__device__ __forceinline__ f32x4 mfma_bf16(s16x8 a, s16x8 b, f32x4 c) {
  return __builtin_amdgcn_mfma_f32_16x16x32_bf16(a, b, c, 0, 0, 0);
}

// ---- explicit-coherence memory ops (sc1 = device scope: meet at LLC, skip L1/L2) ----
// 64-bit VGPR-pair address form; native ext_vector operands (struct types break asm).
__device__ __forceinline__ u32x4 ld_sc1_x4(const void* p) {
  u32x4 d;
  asm volatile("global_load_dwordx4 %0, %1, off sc1"
               : "=v"(d) : "v"((unsigned long long)p) : "memory");
  return d;
}
__device__ __forceinline__ void st_sc1_x4(void* p, u32x4 v) {
  asm volatile("global_store_dwordx4 %0, %1, off sc1"
               :: "v"((unsigned long long)p), "v"(v) : "memory");
}
__device__ __forceinline__ float ld_sc1_f32(const void* p) {
  float d;
  asm volatile("global_load_dword %0, %1, off sc1"
               : "=v"(d) : "v"((unsigned long long)p) : "memory");
  return d;
}
__device__ __forceinline__ void st_sc1_f32(void* p, float v) {
  asm volatile("global_store_dword %0, %1, off sc1"
               :: "v"((unsigned long long)p), "v"(v) : "memory");
}
__device__ __forceinline__ void wait_vm0() { asm volatile("s_waitcnt vmcnt(0)" ::: "memory"); }

// ---------------- params ----------------
struct KParams {
  const float* x;        // [1024][336][16]
  float* out;            // [1024][168]
  unsigned long long* cx;  // per-group barrier counters (stride 32 ULL = 256B)
  unsigned long long* cg;  // global barrier counter
  float* y;              // [1024] decoder feedback (sc1 only)
  u16* h0h[2]; u16* h0l[2];  // h frag-layout [16][1024][32] bf16 hi/lo, ping-pong (sc1 only)
  u16* h1h[2]; u16* h1l[2];
  const u16 *we0h, *we0l;   // [17][2048][32]
  const u16 *we1h, *we1l;   // [32][2048][32]
  const u16 *wd0h, *wd0l;   // [16][2048][32]
  const u16 *wd1h, *wd1l;   // [32][2048][32]
  const u16 *wfh,  *wfl;    // [16][256][32]
  const float *be0, *be1, *bd0, *bd1, *wyp;  // permuted biases [2048], dec0 y-column [2048]
  const float *fcb1, *fcw2, *fcb2;           // raw fp32 from inputs
};

// ---------------- init kernels ----------------
__global__ void zero_ws(uint4* p, long n) {
  uint4 z = {0u, 0u, 0u, 0u};
  for (long i = (long)blockIdx.x * blockDim.x + threadIdx.x; i < n; i += (long)gridDim.x * blockDim.x)
    p[i] = z;
}

// Build fragment-major, gate-interleaved, hi/lo-split weights.
// dst[c][n'][kk], n' = h*4+g  (orig row n = g*512+h), k = c*32+kk.
__global__ void prep_w(const float* __restrict__ Wih, const float* __restrict__ Whh,
                       const float* __restrict__ bias,
                       u16* __restrict__ dhi, u16* __restrict__ dlo,
                       float* __restrict__ bias_p, float* __restrict__ wy_p,
                       int mode, int nchunks) {
  long total = (long)nchunks * 2048 * 32;
  for (long i = (long)blockIdx.x * blockDim.x + threadIdx.x; i < total; i += (long)gridDim.x * blockDim.x) {
    int kk = (int)(i & 31);
    long r1 = i >> 5;
    int n = (int)(r1 & 2047);
    int c = (int)(r1 >> 11);
    int h = n >> 2, g = n & 3;
    int no = g * 512 + h;
    float wv;
    if (mode == 0)      wv = (c < 16) ? Whh[no * 512 + c * 32 + kk] : (kk < 16 ? Wih[no * 16 + kk] : 0.f);
    else if (mode == 1) wv = (c < 16) ? Wih[no * 512 + c * 32 + kk] : Whh[no * 512 + (c - 16) * 32 + kk];
    else                wv = Whh[no * 512 + c * 32 + kk];
    u16 hb = f2bf(wv);
    dhi[i] = hb;
    dlo[i] = f2bf(wv - bf2f(hb));
    if (i < 2048) {
      int nn = (int)i, hh = nn >> 2, gg = nn & 3, noo = gg * 512 + hh;
      bias_p[nn] = bias[noo];
      if (mode == 2) wy_p[nn] = Wih[noo];  // dec_Wih0 is [2048][1]
    }
  }
}

__global__ void prep_fc(const float* __restrict__ W1, u16* __restrict__ dhi, u16* __restrict__ dlo) {
  int total = 16 * 256 * 32;
  for (int i = blockIdx.x * blockDim.x + threadIdx.x; i < total; i += gridDim.x * blockDim.x) {
    int kk = i & 31, n = (i >> 5) & 255, c = i >> 13;
    float wv = W1[n * 512 + c * 32 + kk];
    u16 hb = f2bf(wv);
    dhi[i] = hb;
    dlo[i] = f2bf(wv - bf2f(hb));
  }
}

// ---------------- fence-free wave-level grid barrier ----------------
// All bulk data moves via sc1 ops drained by wait_vm0 before arrival, so no
// cache maintenance (buffer_inv/wbl2) is needed anywhere. 1024 waves arrive:
// 128 per group (32 blocks x 4 waves); group-last bumps cg; waves spin on cg.
__device__ __forceinline__ void gbar(const KParams& P, int grp, unsigned long long bi) {
  wait_vm0();   // this wave's sc1 stores are at the LLC before we arrive
  if ((threadIdx.x & 63) == 0) {
    unsigned long long old =
        __hip_atomic_fetch_add(&P.cx[grp * 32], 1ULL, __ATOMIC_RELAXED, __HIP_MEMORY_SCOPE_AGENT);
    if (old == bi * 128ULL - 1ULL)
      __hip_atomic_fetch_add(P.cg, 1ULL, __ATOMIC_RELAXED, __HIP_MEMORY_SCOPE_AGENT);
    unsigned long long t0 = __builtin_amdgcn_s_memrealtime();
    while (__hip_atomic_load(P.cg, __ATOMIC_RELAXED, __HIP_MEMORY_SCOPE_AGENT) < bi * 8ULL) {
      __builtin_amdgcn_s_sleep(2);
      if (__builtin_amdgcn_s_memrealtime() - t0 > 300000000ULL) {  // ~3 s
        P.out[0] = 1e9f;  // sentinel: barrier timeout
        break;
      }
    }
  }
}

// ---------------- fused gates GEMM + LSTM cell ----------------
// 64m x 128n tile. Wave w owns cols [w*32, w*32+32) (mi 0..1), all 64 rows (mr 0..3).
// A (h, sc1 from LLC) staged via LDS and shared by the 4 waves; B (weights) read
// per-wave directly from L2 (plain cached loads). c-state lives in registers.
template <bool TWOA, bool HASX, bool HASY>
__device__ __forceinline__ void lstm_phase(
    const KParams& P, int m_tile, int n_tile, int nct,
    const u16* A1h, const u16* A1l, const u16* A2h, const u16* A2l,
    const u16* WBh, const u16* WBl,
    const float* __restrict__ bias_p, const float* __restrict__ wyp, int t,
    float (&creg)[8], u16* Hh, u16* Hl, char* smem) {
  const int tid = threadIdx.x;
  const int w = tid >> 6, lane = tid & 63, r = lane & 15, q = lane >> 4;
  const int m0 = m_tile * 64, n0 = n_tile * 128;
  u16* sA = (u16*)smem;                   // [4][64][40] u16 (stride 40 = 16B aligned)
  const int rr = (tid >> 2) & 63, seg = tid & 3;
  const int nst = nct >> 1;

  f32x4 acc[4][2];
#pragma unroll
  for (int mr = 0; mr < 4; ++mr)
#pragma unroll
    for (int mi = 0; mi < 2; ++mi) acc[mr][mi] = (f32x4){0.f, 0.f, 0.f, 0.f};

  u32x4 abuf[4];
  s16x8 bbuf[8];
  const int a_elem_base = (m0 + rr) * 32 + seg * 8;  // u16 elements; + chunk*32768

  auto issue = [&](int s) {
#pragma unroll
    for (int j = 0; j < 4; ++j) {          // j = ch*2+hl
      int ch = j >> 1, hl = j & 1;
      int c = s * 2 + ch;
      const u16* base;
      int cc = c;
      if (TWOA && c >= 16) { base = hl ? A2l : A2h; cc = c - 16; }
      else                 { base = hl ? A1l : A1h; }
      abuf[j] = ld_sc1_x4(base + cc * 32768 + a_elem_base);
    }
#pragma unroll
    for (int ch = 0; ch < 2; ++ch)
#pragma unroll
      for (int hl = 0; hl < 2; ++hl)
#pragma unroll
        for (int mi = 0; mi < 2; ++mi) {
          int c = s * 2 + ch;
          const u16* wb = hl ? WBl : WBh;
          bbuf[(ch * 2 + hl) * 2 + mi] =
              *(const s16x8*)(wb + c * 65536 + (n0 + w * 32 + mi * 16 + r) * 32 + q * 8);
        }
  };

  issue(0);
  for (int s = 0; s < nst; ++s) {
    wait_vm0();                            // stage-s A (asm) at hand; B waits auto-inserted
    u32x4 a0 = abuf[0], a1 = abuf[1], a2 = abuf[2], a3 = abuf[3];
    s16x8 bc[8];
#pragma unroll
    for (int i = 0; i < 8; ++i) bc[i] = bbuf[i];
    __syncthreads();                       // previous readers of sA done
    *(u32x4*)(sA + (0 * 64 + rr) * 40 + seg * 8) = a0;
    *(u32x4*)(sA + (1 * 64 + rr) * 40 + seg * 8) = a1;
    *(u32x4*)(sA + (2 * 64 + rr) * 40 + seg * 8) = a2;
    *(u32x4*)(sA + (3 * 64 + rr) * 40 + seg * 8) = a3;
    __syncthreads();
    if (s + 1 < nst) issue(s + 1);         // prefetch overlaps MFMAs below
#pragma unroll
    for (int ch = 0; ch < 2; ++ch)
#pragma unroll
      for (int mr = 0; mr < 4; ++mr) {
        const s16x8 ah = *(const s16x8*)(sA + ((ch * 2 + 0) * 64 + mr * 16 + r) * 40 + q * 8);
        const s16x8 al = *(const s16x8*)(sA + ((ch * 2 + 1) * 64 + mr * 16 + r) * 40 + q * 8);
#pragma unroll
        for (int mi = 0; mi < 2; ++mi) {
          const s16x8 bh = bc[(ch * 2 + 0) * 2 + mi];
          const s16x8 bl = bc[(ch * 2 + 1) * 2 + mi];
          acc[mr][mi] = mfma_bf16(ah, bh, acc[mr][mi]);
          acc[mr][mi] = mfma_bf16(ah, bl, acc[mr][mi]);
          acc[mr][mi] = mfma_bf16(al, bh, acc[mr][mi]);
        }
      }
  }

  if (HASX) {  // extra K=16 chunk from x_t (padded to 32); weight chunk 16 from L2
#pragma unroll
    for (int mr = 0; mr < 4; ++mr) {
      s16x8 axh, axl;
#pragma unroll
      for (int j = 0; j < 8; ++j) { axh[j] = 0; axl[j] = 0; }
      if (q < 2) {
        const float* xp = P.x + (((long)(m0 + mr * 16 + r) * 336 + t) * 16 + q * 8);
        float4 v0 = *(const float4*)xp;
        float4 v1 = *(const float4*)(xp + 4);
        float vv[8] = {v0.x, v0.y, v0.z, v0.w, v1.x, v1.y, v1.z, v1.w};
#pragma unroll
        for (int j = 0; j < 8; ++j) {
          u16 hb = f2bf(vv[j]);
          axh[j] = (short)hb;
          axl[j] = (short)f2bf(vv[j] - bf2f(hb));
        }
      }
#pragma unroll
      for (int mi = 0; mi < 2; ++mi) {
        long bo = ((long)16 * 2048 + n0 + w * 32 + mi * 16 + r) * 32 + q * 8;
        const s16x8 bh = *(const s16x8*)(WBh + bo);
        const s16x8 bl = *(const s16x8*)(WBl + bo);
        acc[mr][mi] = mfma_bf16(axh, bh, acc[mr][mi]);
        acc[mr][mi] = mfma_bf16(axh, bl, acc[mr][mi]);
        acc[mr][mi] = mfma_bf16(axl, bh, acc[mr][mi]);
      }
    }
  }

  // ---- epilogue: gates -> (c,h); cols are gate-interleaved n'=h*4+g ----
  __syncthreads();
  float* gbuf = (float*)smem;  // [64][129]
#pragma unroll
  for (int mr = 0; mr < 4; ++mr)
#pragma unroll
    for (int mi = 0; mi < 2; ++mi)
#pragma unroll
      for (int reg = 0; reg < 4; ++reg)
        gbuf[(mr * 16 + q * 4 + reg) * 129 + (w * 32 + mi * 16 + r)] = acc[mr][mi][reg];
  float* yb = (float*)(smem + 33024);
  if (HASY) {
    float yv0 = 0.f;
    if (tid < 64) yv0 = ld_sc1_f32(P.y + m0 + tid);
    wait_vm0();
    if (tid < 64) yb[tid] = yv0;
  }
  __syncthreads();
  u16 hbv[8], lbv[8];
#pragma unroll
  for (int kk2 = 0; kk2 < 8; ++kk2) {
    int p = tid + kk2 * 256;
    int ml = p >> 5, hl2 = p & 31;
    const float* gp = gbuf + ml * 129 + hl2 * 4;
    int nb = n0 + hl2 * 4;
    float g0 = gp[0] + bias_p[nb + 0];
    float g1 = gp[1] + bias_p[nb + 1];
    float g2 = gp[2] + bias_p[nb + 2];
    float g3 = gp[3] + bias_p[nb + 3];
    if (HASY) {
      float yv = yb[ml];
      g0 += yv * wyp[nb + 0];
      g1 += yv * wyp[nb + 1];
      g2 += yv * wyp[nb + 2];
      g3 += yv * wyp[nb + 3];
    }
    float ig = sigm(g0), fg = sigm(g1), gg = tanhf(g2), og = sigm(g3);
    float cn = fg * creg[kk2] + ig * gg;
    creg[kk2] = cn;
    float hv = og * tanhf(cn);
    u16 hb = f2bf(hv);
    hbv[kk2] = hb;
    lbv[kk2] = f2bf(hv - bf2f(hb));
  }
  __syncthreads();
  u16* lh = (u16*)smem;             // [64][40]
  u16* ll = (u16*)(smem + 5120);    // [64][40]
#pragma unroll
  for (int kk2 = 0; kk2 < 8; ++kk2) {
    int p = tid + kk2 * 256;
    int ml = p >> 5, hl2 = p & 31;
    lh[ml * 40 + hl2] = hbv[kk2];
    ll[ml * 40 + hl2] = lbv[kk2];
  }
  __syncthreads();
  {
    int mg = rr;  // 0..63
    int eoff = (n_tile * 1024 + m0 + mg) * 32 + seg * 8;  // u16 elements
    st_sc1_x4(Hh + eoff, *(u32x4*)(lh + mg * 40 + seg * 8));
    st_sc1_x4(Hl + eoff, *(u32x4*)(ll + mg * 40 + seg * 8));
  }
}

// ---------------- FC head: pred = relu(relu(h1@W1^T+b1)@W2^T+b2) ----------------
__device__ __forceinline__ void fc_phase(const KParams& P, int b, const u16* Ah, const u16* Al,
                                         int t, char* smem) {
  const int tid = threadIdx.x;
  const int w = tid >> 6, lane = tid & 63, r = lane & 15, q = lane >> 4;
  const int m0 = b * 16;  // 64 blocks x 16 rows
  u16* sA = (u16*)smem;   // [2][16][16][32]
  u32x4 vv[8];
#pragma unroll
  for (int j = 0; j < 8; ++j) {
    int idx = tid + j * 256;
    int hl = idx >> 10, c = (idx >> 6) & 15, rw = (idx >> 2) & 15, sg = idx & 3;
    const u16* src = (hl ? Al : Ah) + (c * 1024 + m0 + rw) * 32 + sg * 8;
    vv[j] = ld_sc1_x4(src);
  }
  wait_vm0();
#pragma unroll
  for (int j = 0; j < 8; ++j) {
    int idx = tid + j * 256;
    int hl = idx >> 10, c = (idx >> 6) & 15, rw = (idx >> 2) & 15, sg = idx & 3;
    *(u32x4*)(sA + ((hl * 16 + c) * 16 + rw) * 32 + sg * 8) = vv[j];
  }
  __syncthreads();
  f32x4 acc[4];
#pragma unroll
  for (int mi = 0; mi < 4; ++mi) acc[mi] = (f32x4){0.f, 0.f, 0.f, 0.f};
  for (int c = 0; c < 16; ++c) {
    const s16x8 ah = *(const s16x8*)(sA + ((0 + c) * 16 + r) * 32 + q * 8);
    const s16x8 al = *(const s16x8*)(sA + ((16 + c) * 16 + r) * 32 + q * 8);
#pragma unroll
    for (int mi = 0; mi < 4; ++mi) {
      int n = w * 64 + mi * 16 + r;
      long bo = ((long)c * 256 + n) * 32 + q * 8;
      const s16x8 bh = *(const s16x8*)(P.wfh + bo);
      const s16x8 bl = *(const s16x8*)(P.wfl + bo);
      acc[mi] = mfma_bf16(ah, bh, acc[mi]);
      acc[mi] = mfma_bf16(ah, bl, acc[mi]);
      acc[mi] = mfma_bf16(al, bh, acc[mi]);
    }
  }
  __syncthreads();
  float* hid = (float*)smem;  // [16][264]
#pragma unroll
  for (int mi = 0; mi < 4; ++mi)
#pragma unroll
    for (int reg = 0; reg < 4; ++reg) {
      int rowi = q * 4 + reg, col = w * 64 + mi * 16 + r;
      hid[rowi * 264 + col] = fmaxf(acc[mi][reg] + P.fcb1[col], 0.f);
    }
  __syncthreads();
  float* part = (float*)(smem + 16 * 264 * 4);  // [16][17]
  {
    int m = tid >> 4, sg = tid & 15;
    float s = 0.f;
#pragma unroll
    for (int j = 0; j < 16; ++j) s += hid[m * 264 + sg * 16 + j] * P.fcw2[sg * 16 + j];
    part[m * 17 + sg] = s;
  }
  __syncthreads();
  if (tid < 16) {
    float s = P.fcb2[0];
    for (int sg = 0; sg < 16; ++sg) s += part[tid * 17 + sg];
    float pred = fmaxf(s, 0.f);
    st_sc1_f32(P.y + m0 + tid, pred);
    P.out[(long)(m0 + tid) * 168 + t] = pred;
  }
}

// ---------------- persistent kernel ----------------
__global__ void __launch_bounds__(TPB, 1) lstm_seq(KParams P) {
  __shared__ __align__(16) char smem[33792];
  const int b = blockIdx.x;
  const int grp = b & 7;                   // barrier group / XCD hint
  const int idx = b >> 3;
  const int n_tile = grp * 2 + (idx & 1);  // each group owns a 256-col slice
  const int m_tile = idx >> 1;
  unsigned long long bi = 0;
  int p0 = 0, p1 = 0;                      // h0[p0]/h1[p1] hold latest h
  float c0r[8], c1r[8];
#pragma unroll
  for (int i = 0; i < 8; ++i) { c0r[i] = 0.f; c1r[i] = 0.f; }

  // encoder, layer-pipelined: phase p computes enc0(t=p) and enc1(t=p-1)
  for (int p = 0; p <= 336; ++p) {
    if (p < 336)
      lstm_phase<false, true, false>(P, m_tile, n_tile, 16, P.h0h[p0], P.h0l[p0], nullptr, nullptr,
                                     P.we0h, P.we0l, P.be0, nullptr, p, c0r,
                                     P.h0h[p0 ^ 1], P.h0l[p0 ^ 1], smem);
    if (p >= 1)
      lstm_phase<true, false, false>(P, m_tile, n_tile, 32, P.h0h[p0], P.h0l[p0], P.h1h[p1],
                                     P.h1l[p1], P.we1h, P.we1l, P.be1, nullptr, 0, c1r,
                                     P.h1h[p1 ^ 1], P.h1l[p1 ^ 1], smem);
    if (p < 336) p0 ^= 1;
    if (p >= 1) p1 ^= 1;
    ++bi; gbar(P, grp, bi);
  }
  // decoder: strict chain dec0 -> dec1 -> fc
  for (int t = 0; t < 168; ++t) {
    lstm_phase<false, false, true>(P, m_tile, n_tile, 16, P.h0h[p0], P.h0l[p0], nullptr, nullptr,
                                   P.wd0h, P.wd0l, P.bd0, P.wyp, 0, c0r,
                                   P.h0h[p0 ^ 1], P.h0l[p0 ^ 1], smem);
    p0 ^= 1; ++bi; gbar(P, grp, bi);
    lstm_phase<true, false, false>(P, m_tile, n_tile, 32, P.h0h[p0], P.h0l[p0], P.h1h[p1],
                                   P.h1l[p1], P.wd1h, P.wd1l, P.bd1, nullptr, 0, c1r,
                                   P.h1h[p1 ^ 1], P.h1l[p1 ^ 1], smem);
    p1 ^= 1; ++bi; gbar(P, grp, bi);
    if (b < 64) fc_phase(P, b, P.h1h[p1], P.h1l[p1], t, smem);
    ++bi; gbar(P, grp, bi);
  }
}

// ---------------- host ----------------
extern "C" void kernel_launch(void* const* d_in, const int* in_sizes, int n_in,
                              void* d_out, int out_size, void* d_ws, size_t ws_size,
                              hipStream_t stream) {
  const float* x     = (const float*)d_in[0];
  const float* eWih0 = (const float*)d_in[1];
  const float* eWhh0 = (const float*)d_in[2];
  const float* eb0   = (const float*)d_in[3];
  const float* eWih1 = (const float*)d_in[4];
  const float* eWhh1 = (const float*)d_in[5];
  const float* eb1   = (const float*)d_in[6];
  const float* dWih0 = (const float*)d_in[7];
  const float* dWhh0 = (const float*)d_in[8];
  const float* db0   = (const float*)d_in[9];
  const float* dWih1 = (const float*)d_in[10];
  const float* dWhh1 = (const float*)d_in[11];
  const float* db1   = (const float*)d_in[12];
  const float* fcW1  = (const float*)d_in[13];
  const float* fcb1  = (const float*)d_in[14];
  const float* fcW2  = (const float*)d_in[15];
  const float* fcb2  = (const float*)d_in[16];

  char* ws = (char*)d_ws;
  unsigned long long* cx = (unsigned long long*)(ws + 0);     // 8 counters, 256B apart
  unsigned long long* cg = (unsigned long long*)(ws + 2048);
  float* y  = (float*)(ws + 4096);
  char* hb = ws + 8192;
  u16* h0h0 = (u16*)(hb + 0L * 1048576);
  u16* h0h1 = (u16*)(hb + 1L * 1048576);
  u16* h0l0 = (u16*)(hb + 2L * 1048576);
  u16* h0l1 = (u16*)(hb + 3L * 1048576);
  u16* h1h0 = (u16*)(hb + 4L * 1048576);
  u16* h1h1 = (u16*)(hb + 5L * 1048576);
  u16* h1l0 = (u16*)(hb + 6L * 1048576);
  u16* h1l1 = (u16*)(hb + 7L * 1048576);
  char* wb = hb + 8L * 1048576;
  u16* we0h = (u16*)wb; wb += 2228224L;
  u16* we0l = (u16*)wb; wb += 2228224L;
  u16* we1h = (u16*)wb; wb += 4194304L;
  u16* we1l = (u16*)wb; wb += 4194304L;
  u16* wd0h = (u16*)wb; wb += 2097152L;
  u16* wd0l = (u16*)wb; wb += 2097152L;
  u16* wd1h = (u16*)wb; wb += 4194304L;
  u16* wd1l = (u16*)wb; wb += 4194304L;
  u16* wfh  = (u16*)wb; wb += 262144L;
  u16* wfl  = (u16*)wb; wb += 262144L;
  float* be0 = (float*)wb; wb += 8192L;
  float* be1 = (float*)wb; wb += 8192L;
  float* bd0 = (float*)wb; wb += 8192L;
  float* bd1 = (float*)wb; wb += 8192L;
  float* wyp = (float*)wb; wb += 8192L;

  long zbytes = 8192L + 8L * 1048576L;  // barrier + y + h buffers
  zero_ws<<<1024, 256, 0, stream>>>((uint4*)ws, zbytes / 16);
  prep_w<<<2048, 256, 0, stream>>>(eWih0, eWhh0, eb0, we0h, we0l, be0, nullptr, 0, 17);
  prep_w<<<2048, 256, 0, stream>>>(eWih1, eWhh1, eb1, we1h, we1l, be1, nullptr, 1, 32);
  prep_w<<<2048, 256, 0, stream>>>(dWih0, dWhh0, db0, wd0h, wd0l, bd0, wyp, 2, 16);
  prep_w<<<2048, 256, 0, stream>>>(dWih1, dWhh1, db1, wd1h, wd1l, bd1, nullptr, 1, 32);
  prep_fc<<<512, 256, 0, stream>>>(fcW1, wfh, wfl);

  KParams P;
  P.x = x; P.out = (float*)d_out; P.cx = cx; P.cg = cg; P.y = y;
  P.h0h[0] = h0h0; P.h0h[1] = h0h1; P.h0l[0] = h0l0; P.h0l[1] = h0l1;
  P.h1h[0] = h1h0; P.h1h[1] = h1h1; P.h1l[0] = h1l0; P.h1l[1] = h1l1;
  P.we0h = we0h; P.we0l = we0l; P.we1h = we1h; P.we1l = we1l;
  P.wd0h = wd0h; P.wd0l = wd0l; P.wd1h = wd1h; P.wd1l = wd1l;
  P.wfh = wfh; P.wfl = wfl;
  P.be0 = be0; P.be1 = be1; P.bd0 = bd0; P.bd1 = bd1; P.wyp = wyp;
  P.fcb1 = fcb1; P.fcw2 = fcW2; P.fcb2 = fcb2;

  lstm_seq<<<NBLK, TPB, 0, stream>>>(P);
}